// Round 7
// baseline (166.760 us; speedup 1.0000x reference)
//
#include <hip/hip_runtime.h>
#include <math.h>

// Problem constants
#define NB 1024        // batch
#define DF 64          // D_FEAT
#define WIN 8192       // WINDOW_SIZE
#define LIR 16382      // ir_len = 2*(WIN-1)
#define TBASE 7681     // t_j = TBASE + j
#define NJ 1024        // padded impulse length (real length 1023)
#define INV_MAXSTEPS (1.0f/2799.0f)
#define TWO_PI 6.28318530717958647692f

// rev-copy geometry: rev[x] = npad[9239-x]; revc[c][x] = rev[x+c], 8 copies, padded to 9248
#define REVLEN 9248
#define SREV 8212      // B[j][i] = rev[8212 - i + j]

// LDS B-window for k_gemm
#define BW_ELEMS 1160
#define BW_CHUNKS 145

using short8 = __attribute__((ext_vector_type(8))) short;
using f32x4  = __attribute__((ext_vector_type(4))) float;

static __device__ __forceinline__ short f2bf(float x) {
    unsigned u = __float_as_uint(x);
    unsigned r = (u + 0x7fffu + ((u >> 16) & 1u)) >> 16;   // RNE
    return (short)r;
}

// ---------------- K_prep: Ct + Waug + head(amps/mean) + gmb zero ----------------
// Ct[j][k] = hann(j+2) * w_k * cos(2*pi*((k*t_j) mod LIR)/LIR), bf16, row j=1023 zero.
// Waug[d][k]: d<65 -> Wc row d; d==65 -> bc; 66..79 -> 0.
#define PREP_CT_BLK 4096
#define PREP_W_BLK  320
#define PREP_H_BLK  4
__global__ __launch_bounds__(256) void k_prep(const float* __restrict__ Wc,
                                              const float* __restrict__ bc,
                                              const float* __restrict__ vel,
                                              const float* __restrict__ Kv,
                                              const float* __restrict__ Wa,
                                              const float* __restrict__ ba,
                                              const float* __restrict__ Wm,
                                              const float* __restrict__ bm,
                                              short* __restrict__ Ct,
                                              short* __restrict__ Waug,
                                              float* __restrict__ amps,
                                              float* __restrict__ mean,
                                              float* __restrict__ out_mean,
                                              unsigned* __restrict__ gmb) {
    int bx = blockIdx.x, tid = threadIdx.x;
    if (bx < PREP_CT_BLK) {
        int flat = bx * 2048 + tid * 8;
        int j = flat >> 13, k0 = flat & 8191;
        int t = TBASE + j;
        int p = (k0 * t) % LIR;                      // exact, k0*t < 2^31
        float hw = 0.5f - 0.5f * __builtin_amdgcn_cosf((float)(j + 2) * (1.0f / 1024.0f));
        if (j == NJ - 1) hw = 0.0f;
        short8 v;
        #pragma unroll
        for (int e = 0; e < 8; ++e) {
            int k = k0 + e;
            float w = (k == 0 || k == LIR / 2) ? (1.0f / (float)LIR) : (2.0f / (float)LIR);
            float c = __builtin_amdgcn_cosf((float)p * (1.0f / (float)LIR)) * w * hw;
            v[e] = f2bf(c);
            p += t; if (p >= LIR) p -= LIR;
        }
        *(short8*)(Ct + flat) = v;
    } else if (bx < PREP_CT_BLK + PREP_W_BLK) {
        int flat = (bx - PREP_CT_BLK) * 2048 + tid * 8;
        int d = flat >> 13, k0 = flat & 8191;
        short8 v;
        #pragma unroll
        for (int e = 0; e < 8; ++e) {
            float x = 0.0f;
            if (d < 65)       x = Wc[(size_t)d * WIN + k0 + e];
            else if (d == 65) x = bc[k0 + e];
            v[e] = f2bf(x);
        }
        *(short8*)(Waug + flat) = v;
    } else if (bx < PREP_CT_BLK + PREP_W_BLK + PREP_H_BLK) {
        int b = (bx - PREP_CT_BLK - PREP_W_BLK) * 256 + tid;
        float sa = ba[0], sm = bm[0];
        #pragma unroll 8
        for (int d = 0; d < DF; ++d) {
            float v = vel[b * DF + d];
            sa = fmaf(v, Wa[d], sa);
            sm = fmaf(v, Wm[d], sm);
        }
        float xk = Kv[b] * INV_MAXSTEPS;
        sa = fmaf(xk, Wa[DF], sa);
        sm = fmaf(xk, Wm[DF], sm);
        amps[b] = 1.0f / (1.0f + expf(-sa));
        float m = tanhf(sm);
        mean[b] = m;
        out_mean[b] = m;
    } else {
        if (tid == 0) gmb[0] = 0u;       // identity for encoded-float atomicMax
    }
}

// ---------------- K1: per-block max of (mean[b] + eps[b,i]) -> encoded atomicMax ----------------
__global__ void k_maxpart(const float* __restrict__ eps, const float* __restrict__ mean,
                          unsigned* __restrict__ gmb) {
    __shared__ float red[256];
    int tid = threadIdx.x;
    float m = -INFINITY;
    const int total4 = NB * WIN / 4;
    const int stride = 1024 * 256;
    const float4* e4 = (const float4*)eps;
    for (int idx = blockIdx.x * 256 + tid; idx < total4; idx += stride) {
        int b = idx >> 11;
        float4 v = e4[idx];
        float mm = fmaxf(fmaxf(v.x, v.y), fmaxf(v.z, v.w));
        m = fmaxf(m, mean[b] + mm);
    }
    red[tid] = m;
    __syncthreads();
    for (int s = 128; s > 0; s >>= 1) {
        if (tid < s) red[tid] = fmaxf(red[tid], red[tid + s]);
        __syncthreads();
    }
    if (tid == 0) {
        unsigned u = __float_as_uint(red[0]);
        unsigned key = (u & 0x80000000u) ? ~u : (u | 0x80000000u);
        atomicMax(gmb, key);
    }
}

// ---------------- K_nrevm: revc[c][x] = bf16(npadval(9239-x-c)) ----------------
__global__ void k_nrevm(const unsigned* __restrict__ gmb, const float* __restrict__ mean,
                        const float* __restrict__ eps, short* __restrict__ revc) {
    int c = blockIdx.y;
    int x = blockIdx.x * 256 + threadIdx.x;
    if (x >= REVLEN) return;
    unsigned key = gmb[0];
    unsigned u = (key & 0x80000000u) ? (key & 0x7FFFFFFFu) : ~key;
    float inv = 1.0f / __uint_as_float(u);
    float m0 = mean[0];
    int q = 9239 - x - c;
    int mm = q - 517;
    float v = ((unsigned)mm < (unsigned)WIN) ? (m0 + eps[mm]) * inv : 0.0f;
    revc[c * REVLEN + x] = f2bf(v);
}

// ---------------- K_gemmA: Apart[ky][j][d] = sum_{k in 128-chunk ky} Ct[j][k]*Waug[d][k] ----------
// LDS-staged (swizzled), grid (8 m-slabs, 64 k-chunks) = 512 blocks, 4 waves.
__global__ __launch_bounds__(256) void k_gemmA(const short* __restrict__ Ct,
                                               const short* __restrict__ Waug,
                                               float* __restrict__ Apart) {
    __shared__ short sA[128 * 128];
    __shared__ short sB[80 * 128];
    int tid = threadIdx.x;
    int j0 = blockIdx.x * 128;
    int ky = blockIdx.y;
    int k0 = ky * 128;

    // stage A: 128 rows x 128 k, XOR-swizzled
    #pragma unroll
    for (int it = 0; it < 8; ++it) {
        int q = it * 256 + tid;                  // octet index
        int row = q >> 4, co = q & 15;
        float4 v = *(const float4*)(Ct + (size_t)(j0 + row) * WIN + k0 + co * 8);
        int db = row * 256 + ((co * 16) ^ ((row & 7) << 4));
        *(float4*)((char*)sA + db) = v;
    }
    // stage B: 80 rows x 128 k, XOR-swizzled
    #pragma unroll
    for (int it = 0; it < 5; ++it) {
        int q = it * 256 + tid;
        int row = q >> 4, co = q & 15;
        float4 v = *(const float4*)(Waug + (size_t)row * WIN + k0 + co * 8);
        int db = row * 256 + ((co * 16) ^ ((row & 7) << 4));
        *(float4*)((char*)sB + db) = v;
    }
    __syncthreads();

    int l = tid & 63, w = tid >> 6;
    int lm = l & 15, lg = l >> 4;

    f32x4 acc[2][5];
    #pragma unroll
    for (int mf = 0; mf < 2; ++mf)
        #pragma unroll
        for (int nf = 0; nf < 5; ++nf)
            #pragma unroll
            for (int r = 0; r < 4; ++r) acc[mf][nf][r] = 0.0f;

    #pragma unroll
    for (int kk = 0; kk < 4; ++kk) {
        int kb = kk * 64 + 16 * lg;              // byte offset of this k-octet
        short8 a[2], b[5];
        #pragma unroll
        for (int mf = 0; mf < 2; ++mf) {
            int row = w * 32 + mf * 16 + lm;
            a[mf] = *(const short8*)((char*)sA + row * 256 + (kb ^ ((row & 7) << 4)));
        }
        #pragma unroll
        for (int nf = 0; nf < 5; ++nf) {
            int d = nf * 16 + lm;
            b[nf] = *(const short8*)((char*)sB + d * 256 + (kb ^ ((d & 7) << 4)));
        }
        #pragma unroll
        for (int nf = 0; nf < 5; ++nf) {
            acc[0][nf] = __builtin_amdgcn_mfma_f32_16x16x32_bf16(a[0], b[nf], acc[0][nf], 0, 0, 0);
            acc[1][nf] = __builtin_amdgcn_mfma_f32_16x16x32_bf16(a[1], b[nf], acc[1][nf], 0, 0, 0);
        }
    }
    // D: row(j) = j0 + w*32 + mf*16 + 4*lg + r, col(d) = nf*16 + lm
    float* base = Apart + (size_t)ky * (NJ * 80);
    #pragma unroll
    for (int mf = 0; mf < 2; ++mf)
        #pragma unroll
        for (int r = 0; r < 4; ++r) {
            int j = j0 + w * 32 + mf * 16 + 4 * lg + r;
            #pragma unroll
            for (int nf = 0; nf < 5; ++nf)
                base[(size_t)j * 80 + nf * 16 + lm] = acc[mf][nf][r];
        }
}

// ---------------- K_red: Aimp[d][j] = sum_ky Apart[ky][j][d] ----------------
__global__ __launch_bounds__(256) void k_red(const float* __restrict__ Apart,
                                             float* __restrict__ Aimp) {
    int flat = blockIdx.x * 256 + threadIdx.x;   // 0 .. 81920
    float s = 0.0f;
    #pragma unroll 8
    for (int ky = 0; ky < 64; ++ky)
        s += Apart[(size_t)ky * (NJ * 80) + flat];
    int j = flat / 80, d = flat - j * 80;
    Aimp[d * NJ + j] = s;
}

// ---------------- K4: imp_bf[b][j] = bf16(xaug[b] . Aimp[:,j]) ----------------
__global__ void k_imp(const float* __restrict__ Aimp, const float* __restrict__ vel,
                      const float* __restrict__ Kv, short* __restrict__ imp_bf) {
    int tid = threadIdx.x;
    int b0 = blockIdx.x * 4;
    float acc[4][4];
    #pragma unroll
    for (int bb = 0; bb < 4; ++bb)
        #pragma unroll
        for (int q = 0; q < 4; ++q) acc[bb][q] = 0.0f;
    for (int d = 0; d < 65; ++d) {
        float xv[4];
        #pragma unroll
        for (int bb = 0; bb < 4; ++bb)
            xv[bb] = (d < DF) ? vel[(b0 + bb) * DF + d] : Kv[b0 + bb] * INV_MAXSTEPS;
        #pragma unroll
        for (int q = 0; q < 4; ++q) {
            float av = Aimp[d * NJ + q * 256 + tid];
            #pragma unroll
            for (int bb = 0; bb < 4; ++bb)
                acc[bb][q] = fmaf(xv[bb], av, acc[bb][q]);
        }
    }
    #pragma unroll
    for (int q = 0; q < 4; ++q) {
        float av = Aimp[65 * NJ + q * 256 + tid];
        #pragma unroll
        for (int bb = 0; bb < 4; ++bb)
            imp_bf[(size_t)(b0 + bb) * NJ + q * 256 + tid] = f2bf(acc[bb][q] + av);
    }
}

// ---------------- K5: LDS-tiled MFMA GEMM (unchanged, proven) ----------------
__global__ __launch_bounds__(256) void k_gemm(const short* __restrict__ imp_bf,
                                              const short* __restrict__ revc,
                                              const float* __restrict__ amps,
                                              float* __restrict__ out) {
    __shared__ short sA[2][128 * 64];
    __shared__ short sB[8 * BW_ELEMS];
    int tid = threadIdx.x;
    int bid = blockIdx.x;
    int m_idx = bid & 7;
    int n_idx = bid >> 3;
    int brow0 = m_idx * 128;
    int icol0 = n_idx * 128;
    int wbase = 8080 - icol0;

    for (int q = tid; q < 8 * BW_CHUNKS; q += 256) {
        int c = q / BW_CHUNKS;
        int u8 = (q - c * BW_CHUNKS) * 8;
        *(float4*)(sB + q * 8) = *(const float4*)(revc + c * REVLEN + wbase + u8);
    }

    float4 st[4];
    #pragma unroll
    for (int it = 0; it < 4; ++it) {
        int q = it * 256 + tid;
        int row = q >> 3, c16 = q & 7;
        st[it] = *(const float4*)(imp_bf + (size_t)(brow0 + row) * NJ + c16 * 8);
    }
    #pragma unroll
    for (int it = 0; it < 4; ++it) {
        int q = it * 256 + tid;
        int row = q >> 3, c16 = q & 7;
        int db = row * 128 + ((c16 * 16) ^ ((row & 7) << 4));
        *(float4*)((char*)sA[0] + db) = st[it];
    }

    int l = tid & 63, w = tid >> 6;
    int wm = w >> 1, wn = w & 1;
    int lm = l & 15, lg = l >> 4;

    int aoff[4][2];
    #pragma unroll
    for (int mf = 0; mf < 4; ++mf)
        #pragma unroll
        for (int kki = 0; kki < 2; ++kki) {
            int row = wm * 64 + mf * 16 + lm;
            int kb = (kki * 32 + 8 * lg) * 2;
            aoff[mf][kki] = row * 64 + ((kb ^ ((row & 7) << 4)) >> 1);
        }
    int boff[4];
    #pragma unroll
    for (int nf = 0; nf < 4; ++nf) {
        int i = icol0 + wn * 64 + nf * 16 + lm;
        int snf = SREV - i;
        int c = snf & 7;
        boff[nf] = c * BW_ELEMS + (snf - c - wbase) + 8 * lg;
    }

    f32x4 acc[4][4];
    #pragma unroll
    for (int mf = 0; mf < 4; ++mf)
        #pragma unroll
        for (int nf = 0; nf < 4; ++nf)
            #pragma unroll
            for (int r = 0; r < 4; ++r) acc[mf][nf][r] = 0.0f;

    int p = 0;
    for (int ch = 0; ch < 16; ++ch) {
        __syncthreads();
        if (ch < 15) {
            int k0n = (ch + 1) * 64;
            #pragma unroll
            for (int it = 0; it < 4; ++it) {
                int q = it * 256 + tid;
                int row = q >> 3, c16 = q & 7;
                st[it] = *(const float4*)(imp_bf + (size_t)(brow0 + row) * NJ + k0n + c16 * 8);
            }
        }
        int k0 = ch * 64;
        #pragma unroll
        for (int kki = 0; kki < 2; ++kki) {
            short8 af[4], bfr[4];
            #pragma unroll
            for (int mf = 0; mf < 4; ++mf)
                af[mf] = *(const short8*)(sA[p] + aoff[mf][kki]);
            #pragma unroll
            for (int nf = 0; nf < 4; ++nf)
                bfr[nf] = *(const short8*)(sB + boff[nf] + k0 + kki * 32);
            #pragma unroll
            for (int mf = 0; mf < 4; ++mf)
                #pragma unroll
                for (int nf = 0; nf < 4; ++nf)
                    acc[mf][nf] = __builtin_amdgcn_mfma_f32_16x16x32_bf16(
                        af[mf], bfr[nf], acc[mf][nf], 0, 0, 0);
        }
        if (ch < 15) {
            #pragma unroll
            for (int it = 0; it < 4; ++it) {
                int q = it * 256 + tid;
                int row = q >> 3, c16 = q & 7;
                int db = row * 128 + ((c16 * 16) ^ ((row & 7) << 4));
                *(float4*)((char*)sA[p ^ 1] + db) = st[it];
            }
        }
        p ^= 1;
    }

    #pragma unroll
    for (int mf = 0; mf < 4; ++mf) {
        #pragma unroll
        for (int r = 0; r < 4; ++r) {
            int row = brow0 + wm * 64 + mf * 16 + 4 * lg + r;
            float a = amps[row];
            #pragma unroll
            for (int nf = 0; nf < 4; ++nf)
                out[(size_t)row * WIN + icol0 + wn * 64 + nf * 16 + lm] = a * acc[mf][nf][r];
        }
    }
}

// ---------------- launch ----------------
extern "C" void kernel_launch(void* const* d_in, const int* in_sizes, int n_in,
                              void* d_out, int out_size, void* d_ws, size_t ws_size,
                              hipStream_t stream) {
    const float* vel = (const float*)d_in[0];
    const float* Kv  = (const float*)d_in[1];
    const float* eps = (const float*)d_in[2];
    const float* Wc  = (const float*)d_in[3];
    const float* bc  = (const float*)d_in[4];
    const float* Wa  = (const float*)d_in[5];
    const float* ba  = (const float*)d_in[6];
    const float* Wm  = (const float*)d_in[7];
    const float* bm  = (const float*)d_in[8];
    float* out = (float*)d_out;

    char* ws = (char*)d_ws;
    float*    amps   = (float*)(ws + 0);               // 4 KB
    float*    mean   = (float*)(ws + 4096);            // 4 KB
    unsigned* gmb    = (unsigned*)(ws + 8192);         // 16 B
    float*    Aimp   = (float*)(ws + 16384);           // 80*1024*4 = 327680
    short*    imp_bf = (short*)(ws + 344064);          // 2 MiB
    short*    Waug   = (short*)(ws + 2441216);         // 80*8192*2 = 1310720
    short*    revc   = (short*)(ws + 3751936);         // 8*9248*2 = 147968
    short*    Ct     = (short*)(ws + 4194304);         // 1024*8192*2 = 16.8 MB
    float*    Apart  = (float*)(ws + 20971520);        // 64*1024*80*4 = 21 MB (ends ~42 MB)

    k_prep   <<<dim3(PREP_CT_BLK + PREP_W_BLK + PREP_H_BLK + 1), dim3(256), 0, stream>>>(
                 Wc, bc, vel, Kv, Wa, ba, Wm, bm, Ct, Waug,
                 amps, mean, out + (size_t)NB * WIN, gmb);
    k_maxpart<<<dim3(1024),   dim3(256), 0, stream>>>(eps, mean, gmb);
    k_nrevm  <<<dim3(37, 8),  dim3(256), 0, stream>>>(gmb, mean, eps, revc);
    k_gemmA  <<<dim3(8, 64),  dim3(256), 0, stream>>>(Ct, Waug, Apart);
    k_red    <<<dim3(320),    dim3(256), 0, stream>>>(Apart, Aimp);
    k_imp    <<<dim3(256),    dim3(256), 0, stream>>>(Aimp, vel, Kv, imp_bf);
    k_gemm   <<<dim3(512),    dim3(256), 0, stream>>>(imp_bf, revc, amps, out);
}

// Round 8
// 154.389 us; speedup vs baseline: 1.0801x; 1.0801x over previous
//
#include <hip/hip_runtime.h>
#include <math.h>

// Problem constants
#define NB 1024        // batch
#define DF 64          // D_FEAT
#define WIN 8192       // WINDOW_SIZE
#define LIR 16382      // ir_len = 2*(WIN-1)
#define TBASE 7681     // t_j = TBASE + j
#define NJ 1024        // padded impulse length (real length 1023)
#define INV_MAXSTEPS (1.0f/2799.0f)

// rev-copy geometry: rev[x] = npad[9239-x]; revc[c][x] = rev[x+c], 8 copies, padded to 9248
#define REVLEN 9248
#define SREV 8212      // B[j][i] = rev[8212 - i + j]

// LDS B-window for k_gemm
#define BW_ELEMS 1160
#define BW_CHUNKS 145

#define KY 32          // Apart partial slices (2 x 128-k chunks per block)

using short8 = __attribute__((ext_vector_type(8))) short;
using f32x4  = __attribute__((ext_vector_type(4))) float;

static __device__ __forceinline__ short f2bf(float x) {
    unsigned u = __float_as_uint(x);
    unsigned r = (u + 0x7fffu + ((u >> 16) & 1u)) >> 16;   // RNE
    return (short)r;
}

// ---------------- K_A: fused {Ct tile gen -> LDS} + {Waug stage -> LDS} + MFMA + head ---------
// gemm blocks (bx<256): Apart[kyb][j][d] = sum_{k in 2 chunks} Ct[j][k]*Waug[d][k]
//   Ct[j][k] = hann(j+2)*w_k*cos(2*pi*((k*t_j) mod LIR)/LIR)  (generated in-kernel, bf16)
//   Waug[d][k]: d<65 -> Wc[d][k]; d==65 -> bc[k]; 66..79 -> 0  (staged from fp32, bf16)
// head blocks (256..259): amps/mean/out_mean.  block 260: gmb = 0.
__global__ __launch_bounds__(256) void k_A(const float* __restrict__ Wc,
                                           const float* __restrict__ bc,
                                           const float* __restrict__ vel,
                                           const float* __restrict__ Kv,
                                           const float* __restrict__ Wa,
                                           const float* __restrict__ ba,
                                           const float* __restrict__ Wm,
                                           const float* __restrict__ bm,
                                           float* __restrict__ Apart,
                                           float* __restrict__ amps,
                                           float* __restrict__ mean,
                                           float* __restrict__ out_mean,
                                           unsigned* __restrict__ gmb) {
    __shared__ short sA[128 * 128];
    __shared__ short sB[80 * 128];
    int bx = blockIdx.x, tid = threadIdx.x;

    if (bx >= 256) {
        if (bx < 260) {
            int b = (bx - 256) * 256 + tid;
            float sa = ba[0], sm = bm[0];
            #pragma unroll 8
            for (int d = 0; d < DF; ++d) {
                float v = vel[b * DF + d];
                sa = fmaf(v, Wa[d], sa);
                sm = fmaf(v, Wm[d], sm);
            }
            float xk = Kv[b] * INV_MAXSTEPS;
            sa = fmaf(xk, Wa[DF], sa);
            sm = fmaf(xk, Wm[DF], sm);
            amps[b] = 1.0f / (1.0f + expf(-sa));
            float m = tanhf(sm);
            mean[b] = m;
            out_mean[b] = m;
        } else if (tid == 0) {
            gmb[0] = 0u;                 // identity for encoded-float atomicMax
        }
        return;
    }

    int m_idx = bx & 7, kyb = bx >> 3;   // 8 j-slabs x 32 ky
    int j0 = m_idx * 128;
    int l = tid & 63, w = tid >> 6;
    int lm = l & 15, lg = l >> 4;

    f32x4 acc[2][5];
    #pragma unroll
    for (int mf = 0; mf < 2; ++mf)
        #pragma unroll
        for (int nf = 0; nf < 5; ++nf)
            #pragma unroll
            for (int r = 0; r < 4; ++r) acc[mf][nf][r] = 0.0f;

    for (int half = 0; half < 2; ++half) {
        int k0 = (kyb * 2 + half) * 128;
        __syncthreads();                 // protect LDS from previous iter's readers

        // ---- generate Ct tile [128 j][128 k] directly into swizzled LDS ----
        #pragma unroll
        for (int it = 0; it < 8; ++it) {
            int q = it * 256 + tid;
            int row = q >> 4, co = q & 15;
            int j = j0 + row;
            int t = TBASE + j;
            int k = k0 + co * 8;
            int p = (k * t) % LIR;       // exact: k*t <= 8184*8704 < 2^31
            float hw = 0.5f - 0.5f * __builtin_amdgcn_cosf((float)(j + 2) * (1.0f / 1024.0f));
            if (j == NJ - 1) hw = 0.0f;
            short8 v;
            #pragma unroll
            for (int e = 0; e < 8; ++e) {
                int kk = k + e;
                float wk = (kk == 0 || kk == LIR / 2) ? (1.0f / (float)LIR) : (2.0f / (float)LIR);
                float c = __builtin_amdgcn_cosf((float)p * (1.0f / (float)LIR)) * wk * hw;
                v[e] = f2bf(c);
                p += t; if (p >= LIR) p -= LIR;
            }
            int db = row * 256 + ((co * 16) ^ ((row & 7) << 4));
            *(short8*)((char*)sA + db) = v;
        }
        // ---- stage Waug tile [80 d][128 k] from fp32 ----
        #pragma unroll
        for (int it = 0; it < 5; ++it) {
            int q = it * 256 + tid;
            int row = q >> 4, co = q & 15;
            short8 v;
            if (row < 65) {
                const float* src = Wc + (size_t)row * WIN + k0 + co * 8;
                #pragma unroll
                for (int e = 0; e < 8; ++e) v[e] = f2bf(src[e]);
            } else if (row == 65) {
                const float* src = bc + k0 + co * 8;
                #pragma unroll
                for (int e = 0; e < 8; ++e) v[e] = f2bf(src[e]);
            } else {
                #pragma unroll
                for (int e = 0; e < 8; ++e) v[e] = 0;
            }
            int db = row * 256 + ((co * 16) ^ ((row & 7) << 4));
            *(short8*)((char*)sB + db) = v;
        }
        __syncthreads();

        // ---- MFMA over this 128-k chunk ----
        #pragma unroll
        for (int kk = 0; kk < 4; ++kk) {
            int kb = kk * 64 + 16 * lg;
            short8 a[2], b[5];
            #pragma unroll
            for (int mf = 0; mf < 2; ++mf) {
                int row = w * 32 + mf * 16 + lm;
                a[mf] = *(const short8*)((char*)sA + row * 256 + (kb ^ ((row & 7) << 4)));
            }
            #pragma unroll
            for (int nf = 0; nf < 5; ++nf) {
                int d = nf * 16 + lm;
                b[nf] = *(const short8*)((char*)sB + d * 256 + (kb ^ ((d & 7) << 4)));
            }
            #pragma unroll
            for (int nf = 0; nf < 5; ++nf) {
                acc[0][nf] = __builtin_amdgcn_mfma_f32_16x16x32_bf16(a[0], b[nf], acc[0][nf], 0, 0, 0);
                acc[1][nf] = __builtin_amdgcn_mfma_f32_16x16x32_bf16(a[1], b[nf], acc[1][nf], 0, 0, 0);
            }
        }
    }

    // D: row(j) = j0 + w*32 + mf*16 + 4*lg + r, col(d) = nf*16 + lm
    float* base = Apart + (size_t)kyb * (NJ * 80);
    #pragma unroll
    for (int mf = 0; mf < 2; ++mf)
        #pragma unroll
        for (int r = 0; r < 4; ++r) {
            int j = j0 + w * 32 + mf * 16 + 4 * lg + r;
            #pragma unroll
            for (int nf = 0; nf < 5; ++nf)
                base[(size_t)j * 80 + nf * 16 + lm] = acc[mf][nf][r];
        }
}

// ---------------- K1: per-block max of (mean[b] + eps[b,i]) -> encoded atomicMax ----------------
__global__ void k_maxpart(const float* __restrict__ eps, const float* __restrict__ mean,
                          unsigned* __restrict__ gmb) {
    __shared__ float red[256];
    int tid = threadIdx.x;
    float m = -INFINITY;
    const int total4 = NB * WIN / 4;
    const int stride = 1024 * 256;
    const float4* e4 = (const float4*)eps;
    for (int idx = blockIdx.x * 256 + tid; idx < total4; idx += stride) {
        int b = idx >> 11;
        float4 v = e4[idx];
        float mm = fmaxf(fmaxf(v.x, v.y), fmaxf(v.z, v.w));
        m = fmaxf(m, mean[b] + mm);
    }
    red[tid] = m;
    __syncthreads();
    for (int s = 128; s > 0; s >>= 1) {
        if (tid < s) red[tid] = fmaxf(red[tid], red[tid + s]);
        __syncthreads();
    }
    if (tid == 0) {
        unsigned u = __float_as_uint(red[0]);
        unsigned key = (u & 0x80000000u) ? ~u : (u | 0x80000000u);
        atomicMax(gmb, key);
    }
}

// ---------------- K_rednrev: fused {Aimp reduce} + {revc build} ----------------
// bx < 320: Aimp[d][j] = sum_ky Apart[ky][j][d]
// bx >= 320 (296 blocks = 8 c x 37): revc[c][x] = bf16(npadval(9239-x-c))
__global__ __launch_bounds__(256) void k_rednrev(const float* __restrict__ Apart,
                                                 float* __restrict__ Aimp,
                                                 const unsigned* __restrict__ gmb,
                                                 const float* __restrict__ mean,
                                                 const float* __restrict__ eps,
                                                 short* __restrict__ revc) {
    int bx = blockIdx.x, tid = threadIdx.x;
    if (bx < 320) {
        int flat = bx * 256 + tid;                   // 0 .. 81920
        float s = 0.0f;
        #pragma unroll 8
        for (int ky = 0; ky < KY; ++ky)
            s += Apart[(size_t)ky * (NJ * 80) + flat];
        int j = flat / 80, d = flat - j * 80;
        Aimp[d * NJ + j] = s;
    } else {
        int r = bx - 320;
        int c = r / 37, xb = r - c * 37;
        int x = xb * 256 + tid;
        if (x >= REVLEN) return;
        unsigned key = gmb[0];
        unsigned u = (key & 0x80000000u) ? (key & 0x7FFFFFFFu) : ~key;
        float inv = 1.0f / __uint_as_float(u);
        float m0 = mean[0];
        int q = 9239 - x - c;
        int mm = q - 517;
        float v = ((unsigned)mm < (unsigned)WIN) ? (m0 + eps[mm]) * inv : 0.0f;
        revc[c * REVLEN + x] = f2bf(v);
    }
}

// ---------------- K4: imp_bf[b][j] = bf16(xaug[b] . Aimp[:,j]) ----------------
__global__ void k_imp(const float* __restrict__ Aimp, const float* __restrict__ vel,
                      const float* __restrict__ Kv, short* __restrict__ imp_bf) {
    int tid = threadIdx.x;
    int b0 = blockIdx.x * 4;
    float acc[4][4];
    #pragma unroll
    for (int bb = 0; bb < 4; ++bb)
        #pragma unroll
        for (int q = 0; q < 4; ++q) acc[bb][q] = 0.0f;
    for (int d = 0; d < 65; ++d) {
        float xv[4];
        #pragma unroll
        for (int bb = 0; bb < 4; ++bb)
            xv[bb] = (d < DF) ? vel[(b0 + bb) * DF + d] : Kv[b0 + bb] * INV_MAXSTEPS;
        #pragma unroll
        for (int q = 0; q < 4; ++q) {
            float av = Aimp[d * NJ + q * 256 + tid];
            #pragma unroll
            for (int bb = 0; bb < 4; ++bb)
                acc[bb][q] = fmaf(xv[bb], av, acc[bb][q]);
        }
    }
    #pragma unroll
    for (int q = 0; q < 4; ++q) {
        float av = Aimp[65 * NJ + q * 256 + tid];
        #pragma unroll
        for (int bb = 0; bb < 4; ++bb)
            imp_bf[(size_t)(b0 + bb) * NJ + q * 256 + tid] = f2bf(acc[bb][q] + av);
    }
}

// ---------------- K5: LDS-tiled MFMA GEMM (unchanged, proven) ----------------
__global__ __launch_bounds__(256) void k_gemm(const short* __restrict__ imp_bf,
                                              const short* __restrict__ revc,
                                              const float* __restrict__ amps,
                                              float* __restrict__ out) {
    __shared__ short sA[2][128 * 64];
    __shared__ short sB[8 * BW_ELEMS];
    int tid = threadIdx.x;
    int bid = blockIdx.x;
    int m_idx = bid & 7;
    int n_idx = bid >> 3;
    int brow0 = m_idx * 128;
    int icol0 = n_idx * 128;
    int wbase = 8080 - icol0;

    for (int q = tid; q < 8 * BW_CHUNKS; q += 256) {
        int c = q / BW_CHUNKS;
        int u8 = (q - c * BW_CHUNKS) * 8;
        *(float4*)(sB + q * 8) = *(const float4*)(revc + c * REVLEN + wbase + u8);
    }

    float4 st[4];
    #pragma unroll
    for (int it = 0; it < 4; ++it) {
        int q = it * 256 + tid;
        int row = q >> 3, c16 = q & 7;
        st[it] = *(const float4*)(imp_bf + (size_t)(brow0 + row) * NJ + c16 * 8);
    }
    #pragma unroll
    for (int it = 0; it < 4; ++it) {
        int q = it * 256 + tid;
        int row = q >> 3, c16 = q & 7;
        int db = row * 128 + ((c16 * 16) ^ ((row & 7) << 4));
        *(float4*)((char*)sA[0] + db) = st[it];
    }

    int l = tid & 63, w = tid >> 6;
    int wm = w >> 1, wn = w & 1;
    int lm = l & 15, lg = l >> 4;

    int aoff[4][2];
    #pragma unroll
    for (int mf = 0; mf < 4; ++mf)
        #pragma unroll
        for (int kki = 0; kki < 2; ++kki) {
            int row = wm * 64 + mf * 16 + lm;
            int kb = (kki * 32 + 8 * lg) * 2;
            aoff[mf][kki] = row * 64 + ((kb ^ ((row & 7) << 4)) >> 1);
        }
    int boff[4];
    #pragma unroll
    for (int nf = 0; nf < 4; ++nf) {
        int i = icol0 + wn * 64 + nf * 16 + lm;
        int snf = SREV - i;
        int c = snf & 7;
        boff[nf] = c * BW_ELEMS + (snf - c - wbase) + 8 * lg;
    }

    f32x4 acc[4][4];
    #pragma unroll
    for (int mf = 0; mf < 4; ++mf)
        #pragma unroll
        for (int nf = 0; nf < 4; ++nf)
            #pragma unroll
            for (int r = 0; r < 4; ++r) acc[mf][nf][r] = 0.0f;

    int p = 0;
    for (int ch = 0; ch < 16; ++ch) {
        __syncthreads();
        if (ch < 15) {
            int k0n = (ch + 1) * 64;
            #pragma unroll
            for (int it = 0; it < 4; ++it) {
                int q = it * 256 + tid;
                int row = q >> 3, c16 = q & 7;
                st[it] = *(const float4*)(imp_bf + (size_t)(brow0 + row) * NJ + k0n + c16 * 8);
            }
        }
        int k0 = ch * 64;
        #pragma unroll
        for (int kki = 0; kki < 2; ++kki) {
            short8 af[4], bfr[4];
            #pragma unroll
            for (int mf = 0; mf < 4; ++mf)
                af[mf] = *(const short8*)(sA[p] + aoff[mf][kki]);
            #pragma unroll
            for (int nf = 0; nf < 4; ++nf)
                bfr[nf] = *(const short8*)(sB + boff[nf] + k0 + kki * 32);
            #pragma unroll
            for (int mf = 0; mf < 4; ++mf)
                #pragma unroll
                for (int nf = 0; nf < 4; ++nf)
                    acc[mf][nf] = __builtin_amdgcn_mfma_f32_16x16x32_bf16(
                        af[mf], bfr[nf], acc[mf][nf], 0, 0, 0);
        }
        if (ch < 15) {
            #pragma unroll
            for (int it = 0; it < 4; ++it) {
                int q = it * 256 + tid;
                int row = q >> 3, c16 = q & 7;
                int db = row * 128 + ((c16 * 16) ^ ((row & 7) << 4));
                *(float4*)((char*)sA[p ^ 1] + db) = st[it];
            }
        }
        p ^= 1;
    }

    #pragma unroll
    for (int mf = 0; mf < 4; ++mf) {
        #pragma unroll
        for (int r = 0; r < 4; ++r) {
            int row = brow0 + wm * 64 + mf * 16 + 4 * lg + r;
            float a = amps[row];
            #pragma unroll
            for (int nf = 0; nf < 4; ++nf)
                out[(size_t)row * WIN + icol0 + wn * 64 + nf * 16 + lm] = a * acc[mf][nf][r];
        }
    }
}

// ---------------- launch ----------------
extern "C" void kernel_launch(void* const* d_in, const int* in_sizes, int n_in,
                              void* d_out, int out_size, void* d_ws, size_t ws_size,
                              hipStream_t stream) {
    const float* vel = (const float*)d_in[0];
    const float* Kv  = (const float*)d_in[1];
    const float* eps = (const float*)d_in[2];
    const float* Wc  = (const float*)d_in[3];
    const float* bc  = (const float*)d_in[4];
    const float* Wa  = (const float*)d_in[5];
    const float* ba  = (const float*)d_in[6];
    const float* Wm  = (const float*)d_in[7];
    const float* bm  = (const float*)d_in[8];
    float* out = (float*)d_out;

    char* ws = (char*)d_ws;
    float*    amps   = (float*)(ws + 0);               // 4 KB
    float*    mean   = (float*)(ws + 4096);            // 4 KB
    unsigned* gmb    = (unsigned*)(ws + 8192);         // 16 B
    float*    Aimp   = (float*)(ws + 16384);           // 80*1024*4 = 327680
    short*    imp_bf = (short*)(ws + 344064);          // 2 MiB
    short*    revc   = (short*)(ws + 2441216);         // 8*9248*2 = 147968
    float*    Apart  = (float*)(ws + 2592768);         // 32*1024*80*4 = 10.5 MB (ends ~13 MB)

    k_A      <<<dim3(261),  dim3(256), 0, stream>>>(Wc, bc, vel, Kv, Wa, ba, Wm, bm,
                                                    Apart, amps, mean,
                                                    out + (size_t)NB * WIN, gmb);
    k_maxpart<<<dim3(1024), dim3(256), 0, stream>>>(eps, mean, gmb);
    k_rednrev<<<dim3(616),  dim3(256), 0, stream>>>(Apart, Aimp, gmb, mean, eps, revc);
    k_imp    <<<dim3(256),  dim3(256), 0, stream>>>(Aimp, vel, Kv, imp_bf);
    k_gemm   <<<dim3(512),  dim3(256), 0, stream>>>(imp_bf, revc, amps, out);
}

// Round 9
// 153.121 us; speedup vs baseline: 1.0891x; 1.0083x over previous
//
#include <hip/hip_runtime.h>
#include <math.h>

// Problem constants
#define NB 1024        // batch
#define DF 64          // D_FEAT
#define WIN 8192       // WINDOW_SIZE
#define LIR 16382      // ir_len = 2*(WIN-1)
#define TBASE 7681     // t_j = TBASE + j
#define NJ 1024        // padded impulse length (real length 1023)
#define INV_MAXSTEPS (1.0f/2799.0f)

// rev-copy geometry: rev[x] = npad[9239-x]; revc[c][x] = rev[x+c], 8 copies, padded to 9248
#define REVLEN 9248
#define SREV 8212      // B[j][i] = rev[8212 - i + j]

// LDS B-window for k_gemm
#define BW_ELEMS 1160
#define BW_CHUNKS 145

#define KY 32          // Apart partial slices (2 x 128-k chunks per block)

using short8 = __attribute__((ext_vector_type(8))) short;
using f32x4  = __attribute__((ext_vector_type(4))) float;

static __device__ __forceinline__ short f2bf(float x) {
    unsigned u = __float_as_uint(x);
    unsigned r = (u + 0x7fffu + ((u >> 16) & 1u)) >> 16;   // RNE
    return (short)r;
}

// ---------------- K_A: fused {Ct tile gen -> LDS} + {Waug stage -> LDS} + MFMA + head ---------
__global__ __launch_bounds__(256) void k_A(const float* __restrict__ Wc,
                                           const float* __restrict__ bc,
                                           const float* __restrict__ vel,
                                           const float* __restrict__ Kv,
                                           const float* __restrict__ Wa,
                                           const float* __restrict__ ba,
                                           const float* __restrict__ Wm,
                                           const float* __restrict__ bm,
                                           float* __restrict__ Apart,
                                           float* __restrict__ amps,
                                           float* __restrict__ mean,
                                           float* __restrict__ out_mean,
                                           unsigned* __restrict__ gmb) {
    __shared__ short sA[128 * 128];
    __shared__ short sB[80 * 128];
    int bx = blockIdx.x, tid = threadIdx.x;

    if (bx >= 256) {
        if (bx < 260) {
            int b = (bx - 256) * 256 + tid;
            float sa = ba[0], sm = bm[0];
            #pragma unroll 8
            for (int d = 0; d < DF; ++d) {
                float v = vel[b * DF + d];
                sa = fmaf(v, Wa[d], sa);
                sm = fmaf(v, Wm[d], sm);
            }
            float xk = Kv[b] * INV_MAXSTEPS;
            sa = fmaf(xk, Wa[DF], sa);
            sm = fmaf(xk, Wm[DF], sm);
            amps[b] = 1.0f / (1.0f + expf(-sa));
            float m = tanhf(sm);
            mean[b] = m;
            out_mean[b] = m;
        } else if (tid == 0) {
            gmb[0] = 0u;                 // identity for encoded-float atomicMax
        }
        return;
    }

    int m_idx = bx & 7, kyb = bx >> 3;   // 8 j-slabs x 32 ky
    int j0 = m_idx * 128;
    int l = tid & 63, w = tid >> 6;
    int lm = l & 15, lg = l >> 4;

    f32x4 acc[2][5];
    #pragma unroll
    for (int mf = 0; mf < 2; ++mf)
        #pragma unroll
        for (int nf = 0; nf < 5; ++nf)
            #pragma unroll
            for (int r = 0; r < 4; ++r) acc[mf][nf][r] = 0.0f;

    for (int half = 0; half < 2; ++half) {
        int k0 = (kyb * 2 + half) * 128;
        __syncthreads();                 // protect LDS from previous iter's readers

        // ---- generate Ct tile [128 j][128 k] directly into swizzled LDS ----
        #pragma unroll
        for (int it = 0; it < 8; ++it) {
            int q = it * 256 + tid;
            int row = q >> 4, co = q & 15;
            int j = j0 + row;
            int t = TBASE + j;
            int k = k0 + co * 8;
            int p = (k * t) % LIR;       // exact: k*t < 2^31
            float hw = 0.5f - 0.5f * __builtin_amdgcn_cosf((float)(j + 2) * (1.0f / 1024.0f));
            if (j == NJ - 1) hw = 0.0f;
            short8 v;
            #pragma unroll
            for (int e = 0; e < 8; ++e) {
                int kk = k + e;
                float wk = (kk == 0 || kk == LIR / 2) ? (1.0f / (float)LIR) : (2.0f / (float)LIR);
                float c = __builtin_amdgcn_cosf((float)p * (1.0f / (float)LIR)) * wk * hw;
                v[e] = f2bf(c);
                p += t; if (p >= LIR) p -= LIR;
            }
            int db = row * 256 + ((co * 16) ^ ((row & 7) << 4));
            *(short8*)((char*)sA + db) = v;
        }
        // ---- stage Waug tile [80 d][128 k] from fp32 ----
        #pragma unroll
        for (int it = 0; it < 5; ++it) {
            int q = it * 256 + tid;
            int row = q >> 4, co = q & 15;
            short8 v;
            if (row < 65) {
                const float* src = Wc + (size_t)row * WIN + k0 + co * 8;
                #pragma unroll
                for (int e = 0; e < 8; ++e) v[e] = f2bf(src[e]);
            } else if (row == 65) {
                const float* src = bc + k0 + co * 8;
                #pragma unroll
                for (int e = 0; e < 8; ++e) v[e] = f2bf(src[e]);
            } else {
                #pragma unroll
                for (int e = 0; e < 8; ++e) v[e] = 0;
            }
            int db = row * 256 + ((co * 16) ^ ((row & 7) << 4));
            *(short8*)((char*)sB + db) = v;
        }
        __syncthreads();

        // ---- MFMA over this 128-k chunk ----
        #pragma unroll
        for (int kk = 0; kk < 4; ++kk) {
            int kb = kk * 64 + 16 * lg;
            short8 a[2], b[5];
            #pragma unroll
            for (int mf = 0; mf < 2; ++mf) {
                int row = w * 32 + mf * 16 + lm;
                a[mf] = *(const short8*)((char*)sA + row * 256 + (kb ^ ((row & 7) << 4)));
            }
            #pragma unroll
            for (int nf = 0; nf < 5; ++nf) {
                int d = nf * 16 + lm;
                b[nf] = *(const short8*)((char*)sB + d * 256 + (kb ^ ((d & 7) << 4)));
            }
            #pragma unroll
            for (int nf = 0; nf < 5; ++nf) {
                acc[0][nf] = __builtin_amdgcn_mfma_f32_16x16x32_bf16(a[0], b[nf], acc[0][nf], 0, 0, 0);
                acc[1][nf] = __builtin_amdgcn_mfma_f32_16x16x32_bf16(a[1], b[nf], acc[1][nf], 0, 0, 0);
            }
        }
    }

    // D: row(j) = j0 + w*32 + mf*16 + 4*lg + r, col(d) = nf*16 + lm
    float* base = Apart + (size_t)kyb * (NJ * 80);
    #pragma unroll
    for (int mf = 0; mf < 2; ++mf)
        #pragma unroll
        for (int r = 0; r < 4; ++r) {
            int j = j0 + w * 32 + mf * 16 + 4 * lg + r;
            #pragma unroll
            for (int nf = 0; nf < 5; ++nf)
                base[(size_t)j * 80 + nf * 16 + lm] = acc[mf][nf][r];
        }
}

// ---------------- K1: per-block max of (mean[b] + eps[b,i]) -> encoded atomicMax ----------------
__global__ void k_maxpart(const float* __restrict__ eps, const float* __restrict__ mean,
                          unsigned* __restrict__ gmb) {
    __shared__ float red[256];
    int tid = threadIdx.x;
    float m = -INFINITY;
    const int total4 = NB * WIN / 4;
    const int stride = 1024 * 256;
    const float4* e4 = (const float4*)eps;
    for (int idx = blockIdx.x * 256 + tid; idx < total4; idx += stride) {
        int b = idx >> 11;
        float4 v = e4[idx];
        float mm = fmaxf(fmaxf(v.x, v.y), fmaxf(v.z, v.w));
        m = fmaxf(m, mean[b] + mm);
    }
    red[tid] = m;
    __syncthreads();
    for (int s = 128; s > 0; s >>= 1) {
        if (tid < s) red[tid] = fmaxf(red[tid], red[tid + s]);
        __syncthreads();
    }
    if (tid == 0) {
        unsigned u = __float_as_uint(red[0]);
        unsigned key = (u & 0x80000000u) ? ~u : (u | 0x80000000u);
        atomicMax(gmb, key);
    }
}

// ---------------- K_rednrev: fused {Aimp reduce} + {revc build} ----------------
__global__ __launch_bounds__(256) void k_rednrev(const float* __restrict__ Apart,
                                                 float* __restrict__ Aimp,
                                                 const unsigned* __restrict__ gmb,
                                                 const float* __restrict__ mean,
                                                 const float* __restrict__ eps,
                                                 short* __restrict__ revc) {
    int bx = blockIdx.x, tid = threadIdx.x;
    if (bx < 320) {
        int flat = bx * 256 + tid;                   // 0 .. 81920
        float s = 0.0f;
        #pragma unroll 8
        for (int ky = 0; ky < KY; ++ky)
            s += Apart[(size_t)ky * (NJ * 80) + flat];
        int j = flat / 80, d = flat - j * 80;
        Aimp[d * NJ + j] = s;
    } else {
        int r = bx - 320;
        int c = r / 37, xb = r - c * 37;
        int x = xb * 256 + tid;
        if (x >= REVLEN) return;
        unsigned key = gmb[0];
        unsigned u = (key & 0x80000000u) ? (key & 0x7FFFFFFFu) : ~key;
        float inv = 1.0f / __uint_as_float(u);
        float m0 = mean[0];
        int q = 9239 - x - c;
        int mm = q - 517;
        float v = ((unsigned)mm < (unsigned)WIN) ? (m0 + eps[mm]) * inv : 0.0f;
        revc[c * REVLEN + x] = f2bf(v);
    }
}

// ---------------- K4: imp_bf[b][j] = bf16(xaug[b] . Aimp[:,j]) ----------------
__global__ void k_imp(const float* __restrict__ Aimp, const float* __restrict__ vel,
                      const float* __restrict__ Kv, short* __restrict__ imp_bf) {
    int tid = threadIdx.x;
    int b0 = blockIdx.x * 4;
    float acc[4][4];
    #pragma unroll
    for (int bb = 0; bb < 4; ++bb)
        #pragma unroll
        for (int q = 0; q < 4; ++q) acc[bb][q] = 0.0f;
    for (int d = 0; d < 65; ++d) {
        float xv[4];
        #pragma unroll
        for (int bb = 0; bb < 4; ++bb)
            xv[bb] = (d < DF) ? vel[(b0 + bb) * DF + d] : Kv[b0 + bb] * INV_MAXSTEPS;
        #pragma unroll
        for (int q = 0; q < 4; ++q) {
            float av = Aimp[d * NJ + q * 256 + tid];
            #pragma unroll
            for (int bb = 0; bb < 4; ++bb)
                acc[bb][q] = fmaf(xv[bb], av, acc[bb][q]);
        }
    }
    #pragma unroll
    for (int q = 0; q < 4; ++q) {
        float av = Aimp[65 * NJ + q * 256 + tid];
        #pragma unroll
        for (int bb = 0; bb < 4; ++bb)
            imp_bf[(size_t)(b0 + bb) * NJ + q * 256 + tid] = f2bf(acc[bb][q] + av);
    }
}

// ---------------- K5: LDS-tiled MFMA GEMM, 64x128 tiles, 1024 blocks (4/CU) ----------------
// out[b][i] = amps[b] * sum_j imp[b][j]*rev[SREV-i+j]
// Block tile 64(M=b) x 128(N=i), BK=64, 4 waves (2x2), wave tile 32x64.
// sA: double-buffered [64][64] bf16, XOR swizzle byte^((row&7)<<4).
// sB: full Toeplitz window, 8 shift-copies x 1160 bf16, staged once.
__global__ __launch_bounds__(256) void k_gemm(const short* __restrict__ imp_bf,
                                              const short* __restrict__ revc,
                                              const float* __restrict__ amps,
                                              float* __restrict__ out) {
    __shared__ short sA[2][64 * 64];
    __shared__ short sB[8 * BW_ELEMS];
    int tid = threadIdx.x;
    int bid = blockIdx.x;
    int m_idx = bid & 15;                // 16 m-slabs; <=2 slabs per XCD (L2-resident A)
    int n_idx = bid >> 4;
    int brow0 = m_idx * 64;
    int icol0 = n_idx * 128;
    int wbase = 8080 - icol0;

    // ---- stage sB (once) ----
    for (int q = tid; q < 8 * BW_CHUNKS; q += 256) {
        int c = q / BW_CHUNKS;
        int u8 = (q - c * BW_CHUNKS) * 8;
        *(float4*)(sB + q * 8) = *(const float4*)(revc + c * REVLEN + wbase + u8);
    }

    // ---- stage A chunk 0: 64 rows x 64 k = 512 octets, 2 per thread ----
    float4 st[2];
    #pragma unroll
    for (int it = 0; it < 2; ++it) {
        int q = it * 256 + tid;
        int row = q >> 3, c16 = q & 7;
        st[it] = *(const float4*)(imp_bf + (size_t)(brow0 + row) * NJ + c16 * 8);
    }
    #pragma unroll
    for (int it = 0; it < 2; ++it) {
        int q = it * 256 + tid;
        int row = q >> 3, c16 = q & 7;
        int db = row * 128 + ((c16 * 16) ^ ((row & 7) << 4));
        *(float4*)((char*)sA[0] + db) = st[it];
    }

    int l = tid & 63, w = tid >> 6;
    int wm = w >> 1, wn = w & 1;
    int lm = l & 15, lg = l >> 4;

    // A-frag LDS offsets (shorts), swizzled
    int aoff[2][2];
    #pragma unroll
    for (int mf = 0; mf < 2; ++mf)
        #pragma unroll
        for (int kki = 0; kki < 2; ++kki) {
            int row = wm * 32 + mf * 16 + lm;
            int kb = (kki * 32 + 8 * lg) * 2;
            aoff[mf][kki] = row * 64 + ((kb ^ ((row & 7) << 4)) >> 1);
        }
    // B-frag LDS offsets (shorts): copy index is k-invariant
    int boff[4];
    #pragma unroll
    for (int nf = 0; nf < 4; ++nf) {
        int i = icol0 + wn * 64 + nf * 16 + lm;
        int snf = SREV - i;
        int c = snf & 7;
        boff[nf] = c * BW_ELEMS + (snf - c - wbase) + 8 * lg;
    }

    f32x4 acc[2][4];
    #pragma unroll
    for (int mf = 0; mf < 2; ++mf)
        #pragma unroll
        for (int nf = 0; nf < 4; ++nf)
            #pragma unroll
            for (int r = 0; r < 4; ++r) acc[mf][nf][r] = 0.0f;

    int p = 0;
    for (int ch = 0; ch < 16; ++ch) {
        __syncthreads();
        if (ch < 15) {
            int k0n = (ch + 1) * 64;
            #pragma unroll
            for (int it = 0; it < 2; ++it) {
                int q = it * 256 + tid;
                int row = q >> 3, c16 = q & 7;
                st[it] = *(const float4*)(imp_bf + (size_t)(brow0 + row) * NJ + k0n + c16 * 8);
            }
        }
        int k0 = ch * 64;
        #pragma unroll
        for (int kki = 0; kki < 2; ++kki) {
            short8 af[2], bfr[4];
            #pragma unroll
            for (int mf = 0; mf < 2; ++mf)
                af[mf] = *(const short8*)(sA[p] + aoff[mf][kki]);
            #pragma unroll
            for (int nf = 0; nf < 4; ++nf)
                bfr[nf] = *(const short8*)(sB + boff[nf] + k0 + kki * 32);
            #pragma unroll
            for (int mf = 0; mf < 2; ++mf)
                #pragma unroll
                for (int nf = 0; nf < 4; ++nf)
                    acc[mf][nf] = __builtin_amdgcn_mfma_f32_16x16x32_bf16(
                        af[mf], bfr[nf], acc[mf][nf], 0, 0, 0);
        }
        if (ch < 15) {
            #pragma unroll
            for (int it = 0; it < 2; ++it) {
                int q = it * 256 + tid;
                int row = q >> 3, c16 = q & 7;
                int db = row * 128 + ((c16 * 16) ^ ((row & 7) << 4));
                *(float4*)((char*)sA[p ^ 1] + db) = st[it];
            }
        }
        p ^= 1;
    }

    // D: row = brow0 + wm*32 + mf*16 + 4*lg + r, col = icol0 + wn*64 + nf*16 + lm
    #pragma unroll
    for (int mf = 0; mf < 2; ++mf) {
        #pragma unroll
        for (int r = 0; r < 4; ++r) {
            int row = brow0 + wm * 32 + mf * 16 + 4 * lg + r;
            float a = amps[row];
            #pragma unroll
            for (int nf = 0; nf < 4; ++nf)
                out[(size_t)row * WIN + icol0 + wn * 64 + nf * 16 + lm] = a * acc[mf][nf][r];
        }
    }
}

// ---------------- launch ----------------
extern "C" void kernel_launch(void* const* d_in, const int* in_sizes, int n_in,
                              void* d_out, int out_size, void* d_ws, size_t ws_size,
                              hipStream_t stream) {
    const float* vel = (const float*)d_in[0];
    const float* Kv  = (const float*)d_in[1];
    const float* eps = (const float*)d_in[2];
    const float* Wc  = (const float*)d_in[3];
    const float* bc  = (const float*)d_in[4];
    const float* Wa  = (const float*)d_in[5];
    const float* ba  = (const float*)d_in[6];
    const float* Wm  = (const float*)d_in[7];
    const float* bm  = (const float*)d_in[8];
    float* out = (float*)d_out;

    char* ws = (char*)d_ws;
    float*    amps   = (float*)(ws + 0);               // 4 KB
    float*    mean   = (float*)(ws + 4096);            // 4 KB
    unsigned* gmb    = (unsigned*)(ws + 8192);         // 16 B
    float*    Aimp   = (float*)(ws + 16384);           // 80*1024*4 = 327680
    short*    imp_bf = (short*)(ws + 344064);          // 2 MiB
    short*    revc   = (short*)(ws + 2441216);         // 8*9248*2 = 147968
    float*    Apart  = (float*)(ws + 2592768);         // 32*1024*80*4 = 10.5 MB (ends ~13 MB)

    k_A      <<<dim3(261),  dim3(256), 0, stream>>>(Wc, bc, vel, Kv, Wa, ba, Wm, bm,
                                                    Apart, amps, mean,
                                                    out + (size_t)NB * WIN, gmb);
    k_maxpart<<<dim3(1024), dim3(256), 0, stream>>>(eps, mean, gmb);
    k_rednrev<<<dim3(616),  dim3(256), 0, stream>>>(Apart, Aimp, gmb, mean, eps, revc);
    k_imp    <<<dim3(256),  dim3(256), 0, stream>>>(Aimp, vel, Kv, imp_bf);
    k_gemm   <<<dim3(1024), dim3(256), 0, stream>>>(imp_bf, revc, amps, out);
}